// Round 23
// baseline (435.659 us; speedup 1.0000x reference)
//
#include <hip/hip_runtime.h>
#include <hip/hip_bf16.h>
#include <cstdint>

#define DF(p) ((const float*)(p))
#define DI(p) ((const int*)(p))

typedef __attribute__((ext_vector_type(8))) short short8v;
typedef __attribute__((ext_vector_type(4))) float f32x4;
typedef __attribute__((ext_vector_type(2))) float f32x2;

static __device__ __forceinline__ float elu_f(float v){
  return v > 0.0f ? v : expm1f(v);
}
static __device__ __forceinline__ float bf_lo(unsigned u){
  union { unsigned u; float f; } c; c.u = u << 16; return c.f;
}
static __device__ __forceinline__ float bf_hi(unsigned u){
  union { unsigned u; float f; } c; c.u = u & 0xFFFF0000u; return c.f;
}
static __device__ __forceinline__ f32x2 bf2(unsigned u){
  union { unsigned u; float f; } lo, hi;
  lo.u = u << 16; hi.u = u & 0xFFFF0000u;
  return f32x2{lo.f, hi.f};
}
static __device__ __forceinline__ unsigned f2b(float f){
  union { float f; unsigned u; } c; c.f = f;
  return (c.u + 0x7FFFu + ((c.u >> 16) & 1u)) >> 16;
}
static __device__ __forceinline__ f32x2 pkfma(float w, f32x2 v, f32x2 c){
  return __builtin_elementwise_fma(f32x2{w, w}, v, c);
}
static __device__ __forceinline__ void acc_edge(
    uint2 u, uint2 wp,
    f32x2& L0, f32x2& H0, f32x2& L1, f32x2& H1,
    f32x2& L2, f32x2& H2, f32x2& L3, f32x2& H3){
  f32x2 vl = bf2(u.x), vh = bf2(u.y);
  float w0=bf_lo(wp.x), w1=bf_hi(wp.x), w2=bf_lo(wp.y), w3=bf_hi(wp.y);
  L0 = pkfma(w0, vl, L0); H0 = pkfma(w0, vh, H0);
  L1 = pkfma(w1, vl, L1); H1 = pkfma(w1, vh, H1);
  L2 = pkfma(w2, vl, L2); H2 = pkfma(w2, vh, H2);
  L3 = pkfma(w3, vl, L3); H3 = pkfma(w3, vh, H3);
}
// one fold step: 2 shfl + 1 packed add (v_pk_add_f32) per accumulator
static __device__ __forceinline__ void fold1(f32x2& a, int m){
  f32x2 t{__shfl_xor(a.x, m, 64), __shfl_xor(a.y, m, 64)};
  a += t;
}
template<int RL, int BND>
static __device__ __forceinline__ void wave_foldB(
    f32x2& a0, f32x2& a1, f32x2& a2, f32x2& a3,
    f32x2& a4, f32x2& a5, f32x2& a6, f32x2& a7){
  #pragma unroll
  for (int m = RL; m < BND; m <<= 1){
    fold1(a0, m); fold1(a1, m); fold1(a2, m); fold1(a3, m);
    fold1(a4, m); fold1(a5, m); fold1(a6, m); fold1(a7, m);
  }
}

// ================= bucket-sort CSR build (no global atomics) =================
// Records stay int4 (ONE 16B scattered store per edge; r20 lesson).
// r23: p4 drops LDS record staging -- bucket region is L2-hot, second pass
// re-reads from global; no CAP limit, tiny LDS, more blocks in flight.
#define NBLK_E 512
#define NBMAX  1024

__global__ __launch_bounds__(256) void p1_bhist4_kernel(
    const int* __restrict__ dst, int* __restrict__ cntB, int E, int NB){
  __shared__ int h[NBMAX];
  const int tid = threadIdx.x;
  for (int k = tid; k < NB; k += 256) h[k] = 0;
  __syncthreads();
  const int4* dst4 = (const int4*)dst;
  const int E4 = E >> 2;
  for (int g = blockIdx.x*256 + tid; g < E4; g += NBLK_E*256){
    int4 d = dst4[g];
    atomicAdd(&h[d.x >> 7], 1);
    atomicAdd(&h[d.y >> 7], 1);
    atomicAdd(&h[d.z >> 7], 1);
    atomicAdd(&h[d.w >> 7], 1);
  }
  if (blockIdx.x == 0 && tid < (E & 3))
    atomicAdd(&h[dst[(E & ~3) + tid] >> 7], 1);
  __syncthreads();
  for (int k = tid; k < NB; k += 256) cntB[blockIdx.x*NBMAX + k] = h[k];
}

__global__ __launch_bounds__(256) void p2_bscan_kernel(
    int* __restrict__ cntB, int* __restrict__ btot, int NB){
  __shared__ int s[256];
  const int k = blockIdx.x;
  const int t = threadIdx.x;
  int v0 = cntB[(2*t  )*NBMAX + k];
  int v1 = cntB[(2*t+1)*NBMAX + k];
  int tsum = v0 + v1;
  s[t] = tsum;
  __syncthreads();
  for (int off = 1; off < 256; off <<= 1){
    int x = (t >= off) ? s[t - off] : 0;
    __syncthreads();
    s[t] += x;
    __syncthreads();
  }
  int excl = s[t] - tsum;
  cntB[(2*t  )*NBMAX + k] = excl;
  cntB[(2*t+1)*NBMAX + k] = excl + v0;
  if (t == 255) btot[k] = s[255];
}

static __device__ __forceinline__ void p3_emit(
    int s, int d, float e0, float e1, float e2, float e3,
    int* off_l, int4* brec){
  unsigned a = f2b(e0) | (f2b(e1) << 16);
  unsigned b = f2b(e2) | (f2b(e3) << 16);
  int pos = atomicAdd(&off_l[d >> 7], 1);
  brec[pos] = make_int4(s, (int)a, (int)b, d);
}

__global__ __launch_bounds__(256) void p3_bscatter4_kernel(
    const int* __restrict__ src, const int* __restrict__ dst,
    const float* __restrict__ ew,
    const int* __restrict__ cntB, const int* __restrict__ btot,
    int4* __restrict__ brec, int E, int NB){
  __shared__ int off_l[NBMAX];
  const int tid = threadIdx.x;
  for (int k = tid; k < NB; k += 256)
    off_l[k] = btot[k] + cntB[blockIdx.x*NBMAX + k];
  __syncthreads();
  const int4*   src4 = (const int4*)src;
  const int4*   dst4 = (const int4*)dst;
  const float4* w0p  = (const float4*)(ew);
  const float4* w1p  = (const float4*)(ew + (size_t)E);
  const float4* w2p  = (const float4*)(ew + 2*(size_t)E);
  const float4* w3p  = (const float4*)(ew + 3*(size_t)E);
  const int E4 = E >> 2;
  for (int g = blockIdx.x*256 + tid; g < E4; g += NBLK_E*256){
    int4 s4 = src4[g];
    int4 d4 = dst4[g];
    float4 w0 = w0p[g], w1 = w1p[g], w2 = w2p[g], w3 = w3p[g];
    p3_emit(s4.x, d4.x, w0.x, w1.x, w2.x, w3.x, off_l, brec);
    p3_emit(s4.y, d4.y, w0.y, w1.y, w2.y, w3.y, off_l, brec);
    p3_emit(s4.z, d4.z, w0.z, w1.z, w2.z, w3.z, off_l, brec);
    p3_emit(s4.w, d4.w, w0.w, w1.w, w2.w, w3.w, off_l, brec);
  }
  if (blockIdx.x == 0 && tid < (E & 3)){
    int e = (E & ~3) + tid;
    p3_emit(src[e], dst[e], ew[e], ew[(size_t)E + e],
            ew[2*(size_t)E + e], ew[3*(size_t)E + e], off_l, brec);
  }
}

// p4: no LDS staging; two passes over the (L2-hot) bucket region
__global__ __launch_bounds__(256) void p4_bsort_kernel(
    const int4* __restrict__ brec, const int* __restrict__ btot,
    int* __restrict__ csr_src, uint2* __restrict__ csr_w,
    int* __restrict__ rowptr, int E, int NB, int N){
  __shared__ int h[128];
  __shared__ int h2[128];
  __shared__ int s[256];
  const int k   = blockIdx.x;
  const int tid = threadIdx.x;
  const int beg = btot[k];
  const int end = (k + 1 < NB) ? btot[k + 1] : E;
  const int count = end - beg;

  if (tid < 128) h[tid] = 0;
  __syncthreads();
  for (int t = tid; t < count; t += 256){
    int4 R = brec[beg + t];
    atomicAdd(&h[R.w & 127], 1);
  }
  __syncthreads();
  int v = (tid < 128) ? h[tid] : 0;
  s[tid] = v;
  __syncthreads();
  for (int off = 1; off < 256; off <<= 1){
    int x = (tid >= off) ? s[tid - off] : 0;
    __syncthreads();
    s[tid] += x;
    __syncthreads();
  }
  if (tid < 128){
    int excl = s[tid] - v;
    h2[tid] = excl;
    int idx = (k << 7) + tid;
    if (idx < N) rowptr[idx] = beg + excl;
  }
  if (k == 0 && tid == 128) rowptr[N] = E;
  __syncthreads();
  for (int t = tid; t < count; t += 256){
    int4 R = brec[beg + t];           // L2-hot second read
    int lp = atomicAdd(&h2[R.w & 127], 1);
    csr_src[beg + lp] = R.x;
    csr_w[beg + lp]   = make_uint2((unsigned)R.y, (unsigned)R.z);
  }
}

// ================= legacy CSR build (fallback, small ws) =================

__global__ void hist_kernel(const int* __restrict__ dst, int* __restrict__ cnt,
                            int* __restrict__ rank, int E){
  int e = blockIdx.x*blockDim.x + threadIdx.x;
  if (e < E) rank[e] = atomicAdd(&cnt[dst[e]], 1);
}

__global__ void scatter_kernel(const int* __restrict__ src, const int* __restrict__ dst,
                               const int* __restrict__ rank, const int* __restrict__ rowptr,
                               int2* __restrict__ csr_se, int E){
  int e = blockIdx.x*blockDim.x + threadIdx.x;
  if (e >= E) return;
  int pos = rowptr[dst[e]] + rank[e];
  csr_se[pos] = make_int2(src[e], e);
}

__global__ void build_kernel(const int2* __restrict__ csr_se, const float* __restrict__ ew,
                             int* __restrict__ csr_src, uint2* __restrict__ csr_w, int E){
  int p = blockIdx.x*blockDim.x + threadIdx.x;
  if (p >= E) return;
  int2 se = csr_se[p];
  csr_src[p] = se.x;
  size_t e = (size_t)se.y;
  unsigned a = f2b(ew[e])               | (f2b(ew[(size_t)E + e]) << 16);
  unsigned b = f2b(ew[2*(size_t)E + e]) | (f2b(ew[3*(size_t)E + e]) << 16);
  csr_w[p] = make_uint2(a, b);
}

__global__ void scan1_kernel(int* __restrict__ data, int* __restrict__ bsum, int total){
  __shared__ int s[256];
  int i = blockIdx.x*256 + threadIdx.x;
  int v = (i < total) ? data[i] : 0;
  s[threadIdx.x] = v;
  __syncthreads();
  for (int off=1; off<256; off<<=1){
    int t = (threadIdx.x >= (unsigned)off) ? s[threadIdx.x - off] : 0;
    __syncthreads();
    s[threadIdx.x] += t;
    __syncthreads();
  }
  if (i < total) data[i] = s[threadIdx.x] - v;
  if (threadIdx.x == 255) bsum[blockIdx.x] = s[255];
}

__global__ void scan2_kernel(int* __restrict__ bsum, int nb){
  __shared__ int s[1024];
  int t = threadIdx.x;
  int v = (t < nb) ? bsum[t] : 0;
  s[t] = v;
  __syncthreads();
  for (int off=1; off<1024; off<<=1){
    int x = (t >= off) ? s[t - off] : 0;
    __syncthreads();
    s[t] += x;
    __syncthreads();
  }
  if (t < nb) bsum[t] = s[t] - v;
}

__global__ void scan3_kernel(int* __restrict__ rowptr, const int* __restrict__ bsum, int total){
  int i = blockIdx.x*256 + threadIdx.x;
  if (i < total) rowptr[i] += bsum[blockIdx.x];
}

// ================= W prep (all 5 layers in one launch) =================

static __device__ __forceinline__ void wtprep_one(
    const float* W, unsigned short* wtp, int t, int DIN, int DOUT, int XPI, int K){
  int j = t / K, k = t % K;
  int r = k / XPI, i = k % XPI;
  float v = (j < DOUT && i < XPI && i < DIN) ? W[(r*DIN + i)*DOUT + j] : 0.f;
  wtp[t] = (unsigned short)f2b(v);
}

__global__ __launch_bounds__(256) void wtprep_all_kernel(
    const float* __restrict__ W1, const float* __restrict__ W2,
    const float* __restrict__ W3, const float* __restrict__ W4,
    const float* __restrict__ W5,
    unsigned short* __restrict__ wtp1, unsigned short* __restrict__ wtp2,
    unsigned short* __restrict__ wtp3, unsigned short* __restrict__ wtp4,
    unsigned short* __restrict__ wtp5){
  int t = blockIdx.x*256 + threadIdx.x;
  if (t < 8192){ wtprep_one(W1, wtp1, t, 64, 20, 64, 256); return; }
  t -= 8192;
  if (t < 2048){ wtprep_one(W2, wtp2, t, 20, 16, 32, 128); return; }
  t -= 2048;
  if (t < 1024){ wtprep_one(W3, wtp3, t, 16, 12, 16, 64); return; }
  t -= 1024;
  if (t < 1024){ wtprep_one(W4, wtp4, t, 12, 8, 16, 64); return; }
  t -= 1024;
  if (t < 1024){ wtprep_one(W5, wtp5, t, 8, 4, 16, 64); return; }
}

// ================= concat (fp32 inputs -> bf16 xcat) =================

__global__ __launch_bounds__(256) void concat_kernel(
    const float* __restrict__ oh, const float* __restrict__ f,
    unsigned short* __restrict__ xcat, int N){
  int i = blockIdx.x*256 + threadIdx.x;
  if (i >= N*64) return;
  int n = i >> 6, j = i & 63;
  float v = (j < 20) ? oh[n*20 + j] : f[n*44 + (j-20)];
  xcat[i] = (unsigned short)f2b(v);
}

// ================= layerA (L1): 4xES-unrolled gather -> z bf16 global =================

template<int XPI, int NPW>
__global__ __launch_bounds__(256) void layerA_kernel(
    const int* __restrict__ rowptr, const int* __restrict__ csr_src,
    const uint2* __restrict__ csr_w, const unsigned short* __restrict__ x,
    unsigned short* __restrict__ z, int N)
{
  constexpr int RL   = XPI/4;
  constexpr int ES   = 64/RL;
  constexpr int NPB  = 4*NPW;
  constexpr int K    = 4*XPI;
  constexpr unsigned ROWB = RL*8;

  const int tid  = threadIdx.x;
  const int wave = tid >> 6;
  const int lane = tid & 63;
  const int sub  = lane / RL;
  const int q4   = lane & (RL - 1);
  const unsigned qoff = (unsigned)q4*8;
  const unsigned char* xb = (const unsigned char*)x;

  #pragma unroll
  for (int t = 0; t < NPW; ++t){
    const int slot = wave*NPW + t;
    const int node = blockIdx.x*NPB + slot;
    if (node < N){
      const int beg = rowptr[node];
      const int end = rowptr[node+1];
      f32x2 AL0{0.f,0.f}, AL1{0.f,0.f}, AL2{0.f,0.f}, AL3{0.f,0.f};
      f32x2 AH0{0.f,0.f}, AH1{0.f,0.f}, AH2{0.f,0.f}, AH3{0.f,0.f};
      int k = beg;
      for (; k + 4*ES <= end; k += 4*ES){
        int kk0 = k + sub, kk1 = k + ES + sub, kk2 = k + 2*ES + sub, kk3 = k + 3*ES + sub;
        int s0 = csr_src[kk0], s1 = csr_src[kk1], s2 = csr_src[kk2], s3 = csr_src[kk3];
        uint2 wp0 = csr_w[kk0], wp1 = csr_w[kk1], wp2 = csr_w[kk2], wp3 = csr_w[kk3];
        uint2 u0 = *(const uint2*)(xb + ((unsigned)s0*ROWB + qoff));
        uint2 u1 = *(const uint2*)(xb + ((unsigned)s1*ROWB + qoff));
        uint2 u2 = *(const uint2*)(xb + ((unsigned)s2*ROWB + qoff));
        uint2 u3 = *(const uint2*)(xb + ((unsigned)s3*ROWB + qoff));
        acc_edge(u0, wp0, AL0, AH0, AL1, AH1, AL2, AH2, AL3, AH3);
        acc_edge(u1, wp1, AL0, AH0, AL1, AH1, AL2, AH2, AL3, AH3);
        acc_edge(u2, wp2, AL0, AH0, AL1, AH1, AL2, AH2, AL3, AH3);
        acc_edge(u3, wp3, AL0, AH0, AL1, AH1, AL2, AH2, AL3, AH3);
      }
      for (; k + 2*ES <= end; k += 2*ES){
        int kk0 = k + sub, kk1 = k + ES + sub;
        int s0 = csr_src[kk0], s1 = csr_src[kk1];
        uint2 wp0 = csr_w[kk0], wp1 = csr_w[kk1];
        uint2 u0 = *(const uint2*)(xb + ((unsigned)s0*ROWB + qoff));
        uint2 u1 = *(const uint2*)(xb + ((unsigned)s1*ROWB + qoff));
        acc_edge(u0, wp0, AL0, AH0, AL1, AH1, AL2, AH2, AL3, AH3);
        acc_edge(u1, wp1, AL0, AH0, AL1, AH1, AL2, AH2, AL3, AH3);
      }
      for (; k < end; k += ES){
        int kk = k + sub;
        int s = 0;
        uint2 wp = make_uint2(0u, 0u);
        if (kk < end){ s = csr_src[kk]; wp = csr_w[kk]; }
        uint2 u = *(const uint2*)(xb + ((unsigned)s*ROWB + qoff));
        acc_edge(u, wp, AL0, AH0, AL1, AH1, AL2, AH2, AL3, AH3);
      }
      wave_foldB<RL, 64>(AL0, AH0, AL1, AH1, AL2, AH2, AL3, AH3);
      if (sub == 0){
        uint2* zp = (uint2*)(z + (size_t)node*K);
        zp[0*RL + q4] = make_uint2(f2b(AL0.x) | (f2b(AL0.y)<<16), f2b(AH0.x) | (f2b(AH0.y)<<16));
        zp[1*RL + q4] = make_uint2(f2b(AL1.x) | (f2b(AL1.y)<<16), f2b(AH1.x) | (f2b(AH1.y)<<16));
        zp[2*RL + q4] = make_uint2(f2b(AL2.x) | (f2b(AL2.y)<<16), f2b(AH2.x) | (f2b(AH2.y)<<16));
        zp[3*RL + q4] = make_uint2(f2b(AL3.x) | (f2b(AL3.y)<<16), f2b(AH3.x) | (f2b(AH3.y)<<16));
      }
    }
  }
}

// ================= gemmB (L1 only): xout = ELU(z @ WtP + b) =================

template<int K, int NJT, int DOUT, int XPO>
__global__ __launch_bounds__(256) void gemmB_kernel(
    const unsigned short* __restrict__ zbuf, const unsigned short* __restrict__ wtp,
    const float* __restrict__ bias, unsigned short* __restrict__ xout, int N)
{
  constexpr int RS   = K*2;
  constexpr int C16  = RS/16;
  constexpr int WT16 = NJT*16*C16;
  constexpr int ZT16 = 16*C16;
  __shared__ __align__(16) unsigned char wt[NJT*16*RS];
  __shared__ __align__(16) unsigned char zt[4][16*RS];

  const int tid  = threadIdx.x;
  const int wave = tid >> 6;
  const int lane = tid & 63;

  const uint4* wsrc = (const uint4*)wtp;
  for (int u = tid; u < WT16; u += 256){
    int row = u / C16, c = u % C16;
    *(uint4*)(wt + ((row*RS + c*16) ^ ((row & 7) << 4))) = wsrc[u];
  }
  const int node_base = (blockIdx.x*4 + wave)*16;
  const uint4* zsrc = (const uint4*)(zbuf + (size_t)node_base*K);
  for (int u = lane; u < ZT16; u += 64){
    int row = u / C16, c = u % C16;
    *(uint4*)(zt[wave] + ((row*RS + c*16) ^ ((row & 7) << 4))) = zsrc[u];
  }
  __syncthreads();

  const int rA = lane & 15;
  const int g  = lane >> 4;
  f32x4 acc[NJT];
  #pragma unroll
  for (int jt = 0; jt < NJT; ++jt) acc[jt] = f32x4{0.f, 0.f, 0.f, 0.f};

  #pragma unroll
  for (int ks = 0; ks < K/32; ++ks){
    short8v a = *(const short8v*)(zt[wave] + ((rA*RS + ks*64 + g*16) ^ ((rA & 7) << 4)));
    #pragma unroll
    for (int jt = 0; jt < NJT; ++jt){
      int rB = rA + jt*16;
      short8v bf = *(const short8v*)(wt + ((rB*RS + ks*64 + g*16) ^ ((rB & 7) << 4)));
      acc[jt] = __builtin_amdgcn_mfma_f32_16x16x32_bf16(a, bf, acc[jt], 0, 0, 0);
    }
  }

  #pragma unroll
  for (int jt = 0; jt < NJT; ++jt){
    int j = rA + jt*16;
    float bj = (j < DOUT) ? bias[j] : 0.f;
    #pragma unroll
    for (int r = 0; r < 4; ++r){
      int node = node_base + g*4 + r;
      if (node < N && j < XPO){
        float v = elu_f(acc[jt][r] + bj);
        xout[(size_t)node*XPO + j] = (unsigned short)f2b(v);
      }
    }
  }
}

// ================= fused layer (L2-L5): partial fold + extended-K MFMA =================

template<int XPI, int NPW, int NJT, int DOUT, int XPO, int CLUST, bool FUSE_MLP>
__global__ __launch_bounds__(256) void fusedB_kernel(
    const int* __restrict__ rowptr, const int* __restrict__ csr_src,
    const uint2* __restrict__ csr_w, const unsigned short* __restrict__ x,
    const unsigned short* __restrict__ wtp, const float* __restrict__ bias,
    unsigned short* __restrict__ xout,
    const float* __restrict__ lw1, const float* __restrict__ lb1,
    const float* __restrict__ lw2, const float* __restrict__ lb2,
    const float* __restrict__ lw3, const float* __restrict__ lb3,
    float* __restrict__ mlp_out, int N)
{
  constexpr int RL   = XPI/4;
  constexpr int ES   = 64/RL;
  constexpr int NPB  = 4*NPW;
  constexpr int K    = 4*XPI;
  constexpr int KE   = K*CLUST;
  constexpr int RS   = KE*2;
  constexpr int C16  = RS/16;
  constexpr int C16B = (K*2)/16;
  constexpr int WT16 = NJT*16*C16;
  constexpr int SUBC = ES/CLUST;
  constexpr int BND  = RL*SUBC;
  constexpr unsigned ROWB = RL*8;
  __shared__ __align__(16) unsigned char wt[NJT*16*RS];
  __shared__ __align__(16) unsigned char zt[16*RS];

  const int tid  = threadIdx.x;
  const int wave = tid >> 6;
  const int lane = tid & 63;

  const uint4* wsrc = (const uint4*)wtp;
  for (int u = tid; u < WT16; u += 256){
    int row = u / C16, c = u % C16;
    *(uint4*)(wt + ((row*RS + c*16) ^ ((row & 7) << 4))) = wsrc[row*C16B + (c & (C16B - 1))];
  }

  const int sub = lane / RL;
  const int q4  = lane & (RL - 1);
  const unsigned qoff = (unsigned)q4*8;
  const unsigned char* xb = (const unsigned char*)x;
  const int node0 = blockIdx.x*NPB;

  int rp[NPW + 1];
  #pragma unroll
  for (int i = 0; i <= NPW; ++i){
    int idx = node0 + wave*NPW + i;
    rp[i] = rowptr[idx > N ? N : idx];
  }

  #pragma unroll
  for (int t = 0; t < NPW; ++t){
    const int slot = wave*NPW + t;
    const int node = node0 + slot;
    if (node < N){
      const int beg = rp[t];
      const int end = rp[t+1];
      f32x2 AL0{0.f,0.f}, AL1{0.f,0.f}, AL2{0.f,0.f}, AL3{0.f,0.f};
      f32x2 AH0{0.f,0.f}, AH1{0.f,0.f}, AH2{0.f,0.f}, AH3{0.f,0.f};
      int k = beg;
      for (; k + 2*ES <= end; k += 2*ES){
        int kk0 = k + sub, kk1 = k + ES + sub;
        int s0 = csr_src[kk0], s1 = csr_src[kk1];
        uint2 wp0 = csr_w[kk0], wp1 = csr_w[kk1];
        uint2 u0 = *(const uint2*)(xb + ((unsigned)s0*ROWB + qoff));
        uint2 u1 = *(const uint2*)(xb + ((unsigned)s1*ROWB + qoff));
        acc_edge(u0, wp0, AL0, AH0, AL1, AH1, AL2, AH2, AL3, AH3);
        acc_edge(u1, wp1, AL0, AH0, AL1, AH1, AL2, AH2, AL3, AH3);
      }
      for (; k < end; k += ES){
        int kk = k + sub;
        int s = 0;
        uint2 wp = make_uint2(0u, 0u);
        if (kk < end){ s = csr_src[kk]; wp = csr_w[kk]; }
        uint2 u = *(const uint2*)(xb + ((unsigned)s*ROWB + qoff));
        acc_edge(u, wp, AL0, AH0, AL1, AH1, AL2, AH2, AL3, AH3);
      }
      wave_foldB<RL, BND>(AL0, AH0, AL1, AH1, AL2, AH2, AL3, AH3);
      if ((sub & (SUBC - 1)) == 0){
        const int cid = sub / SUBC;
        uint2 c0 = make_uint2(f2b(AL0.x) | (f2b(AL0.y)<<16), f2b(AH0.x) | (f2b(AH0.y)<<16));
        uint2 c1 = make_uint2(f2b(AL1.x) | (f2b(AL1.y)<<16), f2b(AH1.x) | (f2b(AH1.y)<<16));
        uint2 c2 = make_uint2(f2b(AL2.x) | (f2b(AL2.y)<<16), f2b(AH2.x) | (f2b(AH2.y)<<16));
        uint2 c3 = make_uint2(f2b(AL3.x) | (f2b(AL3.y)<<16), f2b(AH3.x) | (f2b(AH3.y)<<16));
        const int sw = (slot & 7) << 4;
        const int kb = cid*K*2;
        int bc0 = kb + (0*XPI + q4*4)*2;
        int bc1 = kb + (1*XPI + q4*4)*2;
        int bc2 = kb + (2*XPI + q4*4)*2;
        int bc3 = kb + (3*XPI + q4*4)*2;
        *(uint2*)(zt + (((slot*RS + (bc0 & ~15)) ^ sw) + (bc0 & 15))) = c0;
        *(uint2*)(zt + (((slot*RS + (bc1 & ~15)) ^ sw) + (bc1 & 15))) = c1;
        *(uint2*)(zt + (((slot*RS + (bc2 & ~15)) ^ sw) + (bc2 & 15))) = c2;
        *(uint2*)(zt + (((slot*RS + (bc3 & ~15)) ^ sw) + (bc3 & 15))) = c3;
      }
    }
  }
  __syncthreads();

  if (wave == 0){
    const int rA = lane & 15;
    const int g  = lane >> 4;
    f32x4 acc[NJT];
    #pragma unroll
    for (int jt = 0; jt < NJT; ++jt) acc[jt] = f32x4{0.f, 0.f, 0.f, 0.f};

    #pragma unroll
    for (int ks = 0; ks < KE/32; ++ks){
      short8v a = *(const short8v*)(zt + ((rA*RS + ks*64 + g*16) ^ ((rA & 7) << 4)));
      #pragma unroll
      for (int jt = 0; jt < NJT; ++jt){
        int rB = rA + jt*16;
        short8v bf = *(const short8v*)(wt + ((rB*RS + ks*64 + g*16) ^ ((rB & 7) << 4)));
        acc[jt] = __builtin_amdgcn_mfma_f32_16x16x32_bf16(a, bf, acc[jt], 0, 0, 0);
      }
    }

    if (!FUSE_MLP){
      #pragma unroll
      for (int jt = 0; jt < NJT; ++jt){
        int j = rA + jt*16;
        float bj = (j < DOUT) ? bias[j] : 0.f;
        #pragma unroll
        for (int r = 0; r < 4; ++r){
          int row = g*4 + r;
          int node = node0 + row;
          if (row < NPB && node < N && j < XPO){
            float v = elu_f(acc[jt][r] + bj);
            xout[(size_t)node*XPO + j] = (unsigned short)f2b(v);
          }
        }
      }
    } else {
      float bj = (rA < DOUT) ? bias[rA] : 0.f;
      float val[4];
      #pragma unroll
      for (int r = 0; r < 4; ++r) val[r] = elu_f(acc[0][r] + bj);
      const int base = lane & 48;
      float x0 = 0.f, x1 = 0.f, x2 = 0.f, x3 = 0.f;
      #pragma unroll
      for (int q = 0; q < 4; ++q){
        float t0 = __shfl(val[q], base + 0, 64);
        float t1 = __shfl(val[q], base + 1, 64);
        float t2 = __shfl(val[q], base + 2, 64);
        float t3 = __shfl(val[q], base + 3, 64);
        if (rA == q){ x0 = t0; x1 = t1; x2 = t2; x3 = t3; }
      }
      if (rA < 4){
        int node = node0 + g*4 + rA;
        if (node < N){
          float xin[4] = {x0, x1, x2, x3};
          float h1[8];
          #pragma unroll
          for (int j = 0; j < 8; ++j){
            float a = lb1[j];
            #pragma unroll
            for (int i = 0; i < 4; ++i) a += xin[i]*lw1[i*8 + j];
            h1[j] = elu_f(a);
          }
          float h2[4];
          #pragma unroll
          for (int j = 0; j < 4; ++j){
            float a = lb2[j];
            #pragma unroll
            for (int i = 0; i < 8; ++i) a += h1[i]*lw2[i*4 + j];
            h2[j] = elu_f(a);
          }
          float a = lb3[0];
          #pragma unroll
          for (int i = 0; i < 4; ++i) a += h2[i]*lw3[i];
          mlp_out[node] = 1.0f / (1.0f + expf(-a));
        }
      }
    }
  }
}

// ================= standalone MLP (legacy fallback path only) =================

__global__ __launch_bounds__(256) void mlp_kernel(
    const unsigned short* __restrict__ x,
    const float* __restrict__ lw1, const float* __restrict__ lb1,
    const float* __restrict__ lw2, const float* __restrict__ lb2,
    const float* __restrict__ lw3, const float* __restrict__ lb3,
    float* __restrict__ out, int N){
  int n = blockIdx.x*blockDim.x + threadIdx.x;
  if (n >= N) return;
  uint2 u = ((const uint2*)x)[n];
  float x0[4] = {bf_lo(u.x), bf_hi(u.x), bf_lo(u.y), bf_hi(u.y)};
  float h1[8];
  #pragma unroll
  for (int j=0;j<8;j++){
    float a = lb1[j];
    #pragma unroll
    for (int i=0;i<4;i++) a += x0[i]*lw1[i*8+j];
    h1[j] = elu_f(a);
  }
  float h2[4];
  #pragma unroll
  for (int j=0;j<4;j++){
    float a = lb2[j];
    #pragma unroll
    for (int i=0;i<8;i++) a += h1[i]*lw2[i*4+j];
    h2[j] = elu_f(a);
  }
  float a = lb3[0];
  #pragma unroll
  for (int i=0;i<4;i++) a += h2[i]*lw3[i];
  out[n] = 1.0f / (1.0f + expf(-a));
}

// ================= launch =================

extern "C" void kernel_launch(void* const* d_in, const int* in_sizes, int n_in,
                              void* d_out, int out_size, void* d_ws, size_t ws_size,
                              hipStream_t stream){
  const float* one_hot  = DF(d_in[0]);
  const float* features = DF(d_in[1]);
  const int*   src      = DI(d_in[3]);
  const int*   dst      = DI(d_in[4]);
  const float* ew       = DF(d_in[5]);
  const float* W1 = DF(d_in[6]);  const float* b1 = DF(d_in[7]);
  const float* W2 = DF(d_in[8]);  const float* b2 = DF(d_in[9]);
  const float* W3 = DF(d_in[10]); const float* b3 = DF(d_in[11]);
  const float* W4 = DF(d_in[12]); const float* b4 = DF(d_in[13]);
  const float* W5 = DF(d_in[14]); const float* b5 = DF(d_in[15]);
  const float* lw1 = DF(d_in[16]); const float* lb1 = DF(d_in[17]);
  const float* lw2 = DF(d_in[18]); const float* lb2 = DF(d_in[19]);
  const float* lw3 = DF(d_in[20]); const float* lb3 = DF(d_in[21]);
  float* out = (float*)d_out;

  const int N = in_sizes[0] / 20;   // 100000
  const int E = in_sizes[3];        // 3200000
  const int NB = (N + 127) >> 7;
  const int zN = ((N + 63)/64)*64;

  auto align = [](size_t x){ return (x + 255) & ~((size_t)255); };
  char* ws = (char*)d_ws;
  size_t off = 0;
  int*    rowptr  = (int*)(ws + off);    off = align(off + (size_t)(N+1)*4);
  int*    bsum    = (int*)(ws + off);    off = align(off + 4096);
  int*    csr_src = (int*)(ws + off);    off = align(off + (size_t)E*4);
  uint2*  csr_w   = (uint2*)(ws + off);  off = align(off + (size_t)E*8);
  unsigned short* wtp1 = (unsigned short*)(ws + off); off = align(off + 32*256*2);
  unsigned short* wtp2 = (unsigned short*)(ws + off); off = align(off + 16*128*2);
  unsigned short* wtp3 = (unsigned short*)(ws + off); off = align(off + 16*64*2);
  unsigned short* wtp4 = (unsigned short*)(ws + off); off = align(off + 16*64*2);
  unsigned short* wtp5 = (unsigned short*)(ws + off); off = align(off + 16*64*2);
  char*   regD    = ws + off;            off = align(off + (size_t)E*8);
  int2*   csr_se  = (int2*)regD;
  unsigned short* xcat = (unsigned short*)regD;
  char*   regE    = ws + off;            off = align(off + (size_t)E*4);
  int*    rank    = (int*)regE;
  unsigned short* xA = (unsigned short*)regE;
  unsigned short* xB = (unsigned short*)(ws + off); off = align(off + (size_t)N*16*2);
  unsigned short* xC = (unsigned short*)(ws + off); off = align(off + (size_t)N*16*2);
  char*   regF    = ws + off;            // legacy zbuf region
  size_t  off1 = align(off + (size_t)E*8);
  int*    cntB    = (int*)(ws + off1);   off1 = align(off1 + (size_t)NBLK_E*NBMAX*4);
  int*    btot    = (int*)(ws + off1);   off1 = align(off1 + (size_t)NBMAX*4);
  char*   regG    = ws + off1;
  int4*   brec    = (int4*)regG;
  size_t gsz = (size_t)E*16; if ((size_t)zN*512 > gsz) gsz = (size_t)zN*512;
  off1 = align(off1 + gsz);
  size_t  need_bucket = off1;

  const int TB = 256;
  const int nbE = (E + TB - 1) / TB;
  const int nbN = (N + TB - 1) / TB;
  const int total = N + 1;
  const int nb1 = (total + 255) / 256;
  const bool bucket_path = (ws_size >= need_bucket) && (NB <= NBMAX);
  unsigned short* zbuf = bucket_path ? (unsigned short*)regG : (unsigned short*)regF;

  wtprep_all_kernel<<<(13312 + 255)/256, TB, 0, stream>>>(
      W1, W2, W3, W4, W5, wtp1, wtp2, wtp3, wtp4, wtp5);

  if (bucket_path){
    p1_bhist4_kernel<<<NBLK_E, TB, 0, stream>>>(dst, cntB, E, NB);
    p2_bscan_kernel<<<NB, TB, 0, stream>>>(cntB, btot, NB);
    scan2_kernel<<<1, 1024, 0, stream>>>(btot, NB);
    p3_bscatter4_kernel<<<NBLK_E, TB, 0, stream>>>(src, dst, ew, cntB, btot, brec, E, NB);
    p4_bsort_kernel<<<NB, TB, 0, stream>>>(brec, btot, csr_src, csr_w, rowptr, E, NB, N);
  } else {
    hipMemsetAsync(rowptr, 0, (size_t)(N+1)*4, stream);
    hist_kernel<<<nbE, TB, 0, stream>>>(dst, rowptr, rank, E);
    scan1_kernel<<<nb1, 256, 0, stream>>>(rowptr, bsum, total);
    scan2_kernel<<<1, 1024, 0, stream>>>(bsum, nb1);
    scan3_kernel<<<nb1, 256, 0, stream>>>(rowptr, bsum, total);
    scatter_kernel<<<nbE, TB, 0, stream>>>(src, dst, rank, rowptr, csr_se, E);
    build_kernel<<<nbE, TB, 0, stream>>>(csr_se, ew, csr_src, csr_w, E);
  }

  concat_kernel<<<(N*64 + TB - 1)/TB, TB, 0, stream>>>(one_hot, features, xcat, N);

  const int NBB = (N + 63)/64;
  // L1: 64 -> 20 (split: layerA -> global z -> gemmB)
  layerA_kernel<64,1><<<(N+3)/4, TB, 0, stream>>>(rowptr, csr_src, csr_w, xcat, zbuf, N);
  gemmB_kernel<256,2,20,32><<<NBB, TB, 0, stream>>>(zbuf, wtp1, b1, xA, N);
  // L2-L4: fused, partial fold (CLUST clusters) + extended-K MFMA
  fusedB_kernel<32,2,1,16,16,2,false><<<(N+7)/8,   TB, 0, stream>>>(
      rowptr, csr_src, csr_w, xA, wtp2, b2, xB,
      nullptr, nullptr, nullptr, nullptr, nullptr, nullptr, nullptr, N);
  fusedB_kernel<16,4,1,12,16,4,false><<<(N+15)/16, TB, 0, stream>>>(
      rowptr, csr_src, csr_w, xB, wtp3, b3, xC,
      nullptr, nullptr, nullptr, nullptr, nullptr, nullptr, nullptr, N);
  fusedB_kernel<16,4,1, 8,16,4,false><<<(N+15)/16, TB, 0, stream>>>(
      rowptr, csr_src, csr_w, xC, wtp4, b4, xA,
      nullptr, nullptr, nullptr, nullptr, nullptr, nullptr, nullptr, N);
  // L5 + MLP fused: writes sigmoid output directly
  fusedB_kernel<16,4,1, 4, 4,4,true><<<(N+15)/16, TB, 0, stream>>>(
      rowptr, csr_src, csr_w, xA, wtp5, b5, nullptr,
      lw1, lb1, lw2, lb2, lw3, lb3, out, N);
}

// Round 24
// 416.085 us; speedup vs baseline: 1.0470x; 1.0470x over previous
//
#include <hip/hip_runtime.h>
#include <hip/hip_bf16.h>
#include <cstdint>

#define DF(p) ((const float*)(p))
#define DI(p) ((const int*)(p))

typedef __attribute__((ext_vector_type(8))) short short8v;
typedef __attribute__((ext_vector_type(4))) float f32x4;
typedef __attribute__((ext_vector_type(2))) float f32x2;

static __device__ __forceinline__ float elu_f(float v){
  return v > 0.0f ? v : expm1f(v);
}
static __device__ __forceinline__ float bf_lo(unsigned u){
  union { unsigned u; float f; } c; c.u = u << 16; return c.f;
}
static __device__ __forceinline__ float bf_hi(unsigned u){
  union { unsigned u; float f; } c; c.u = u & 0xFFFF0000u; return c.f;
}
static __device__ __forceinline__ f32x2 bf2(unsigned u){
  union { unsigned u; float f; } lo, hi;
  lo.u = u << 16; hi.u = u & 0xFFFF0000u;
  return f32x2{lo.f, hi.f};
}
static __device__ __forceinline__ unsigned f2b(float f){
  union { float f; unsigned u; } c; c.f = f;
  return (c.u + 0x7FFFu + ((c.u >> 16) & 1u)) >> 16;
}
static __device__ __forceinline__ f32x2 pkfma(float w, f32x2 v, f32x2 c){
  return __builtin_elementwise_fma(f32x2{w, w}, v, c);
}
static __device__ __forceinline__ void acc_edge(
    uint2 u, uint2 wp,
    f32x2& L0, f32x2& H0, f32x2& L1, f32x2& H1,
    f32x2& L2, f32x2& H2, f32x2& L3, f32x2& H3){
  f32x2 vl = bf2(u.x), vh = bf2(u.y);
  float w0=bf_lo(wp.x), w1=bf_hi(wp.x), w2=bf_lo(wp.y), w3=bf_hi(wp.y);
  L0 = pkfma(w0, vl, L0); H0 = pkfma(w0, vh, H0);
  L1 = pkfma(w1, vl, L1); H1 = pkfma(w1, vh, H1);
  L2 = pkfma(w2, vl, L2); H2 = pkfma(w2, vh, H2);
  L3 = pkfma(w3, vl, L3); H3 = pkfma(w3, vh, H3);
}
template<int RL, int BND>
static __device__ __forceinline__ void wave_foldB(
    f32x2& a0, f32x2& a1, f32x2& a2, f32x2& a3,
    f32x2& a4, f32x2& a5, f32x2& a6, f32x2& a7){
  #pragma unroll
  for (int m = RL; m < BND; m <<= 1){
    a0.x += __shfl_xor(a0.x, m, 64); a0.y += __shfl_xor(a0.y, m, 64);
    a1.x += __shfl_xor(a1.x, m, 64); a1.y += __shfl_xor(a1.y, m, 64);
    a2.x += __shfl_xor(a2.x, m, 64); a2.y += __shfl_xor(a2.y, m, 64);
    a3.x += __shfl_xor(a3.x, m, 64); a3.y += __shfl_xor(a3.y, m, 64);
    a4.x += __shfl_xor(a4.x, m, 64); a4.y += __shfl_xor(a4.y, m, 64);
    a5.x += __shfl_xor(a5.x, m, 64); a5.y += __shfl_xor(a5.y, m, 64);
    a6.x += __shfl_xor(a6.x, m, 64); a6.y += __shfl_xor(a6.y, m, 64);
    a7.x += __shfl_xor(a7.x, m, 64); a7.y += __shfl_xor(a7.y, m, 64);
  }
}

// ================= bucket-sort CSR build (no global atomics) =================
// Records stay int4 (ONE 16B scattered store per edge; r20 lesson).
// p4 keeps LDS record staging (r23 no-staging regressed: brec spans 51MB,
// NOT L2-hot on second pass). p1/p3 vectorized 4 edges/thread (r22 win).
#define NBLK_E 512
#define NBMAX  1024
#define CAP    4864

__global__ __launch_bounds__(256) void p1_bhist4_kernel(
    const int* __restrict__ dst, int* __restrict__ cntB, int E, int NB){
  __shared__ int h[NBMAX];
  const int tid = threadIdx.x;
  for (int k = tid; k < NB; k += 256) h[k] = 0;
  __syncthreads();
  const int4* dst4 = (const int4*)dst;
  const int E4 = E >> 2;
  for (int g = blockIdx.x*256 + tid; g < E4; g += NBLK_E*256){
    int4 d = dst4[g];
    atomicAdd(&h[d.x >> 7], 1);
    atomicAdd(&h[d.y >> 7], 1);
    atomicAdd(&h[d.z >> 7], 1);
    atomicAdd(&h[d.w >> 7], 1);
  }
  if (blockIdx.x == 0 && tid < (E & 3))
    atomicAdd(&h[dst[(E & ~3) + tid] >> 7], 1);
  __syncthreads();
  for (int k = tid; k < NB; k += 256) cntB[blockIdx.x*NBMAX + k] = h[k];
}

__global__ __launch_bounds__(256) void p2_bscan_kernel(
    int* __restrict__ cntB, int* __restrict__ btot, int NB){
  __shared__ int s[256];
  const int k = blockIdx.x;
  const int t = threadIdx.x;
  int v0 = cntB[(2*t  )*NBMAX + k];
  int v1 = cntB[(2*t+1)*NBMAX + k];
  int tsum = v0 + v1;
  s[t] = tsum;
  __syncthreads();
  for (int off = 1; off < 256; off <<= 1){
    int x = (t >= off) ? s[t - off] : 0;
    __syncthreads();
    s[t] += x;
    __syncthreads();
  }
  int excl = s[t] - tsum;
  cntB[(2*t  )*NBMAX + k] = excl;
  cntB[(2*t+1)*NBMAX + k] = excl + v0;
  if (t == 255) btot[k] = s[255];
}

static __device__ __forceinline__ void p3_emit(
    int s, int d, float e0, float e1, float e2, float e3,
    int* off_l, int4* brec){
  unsigned a = f2b(e0) | (f2b(e1) << 16);
  unsigned b = f2b(e2) | (f2b(e3) << 16);
  int pos = atomicAdd(&off_l[d >> 7], 1);
  brec[pos] = make_int4(s, (int)a, (int)b, d);
}

__global__ __launch_bounds__(256) void p3_bscatter4_kernel(
    const int* __restrict__ src, const int* __restrict__ dst,
    const float* __restrict__ ew,
    const int* __restrict__ cntB, const int* __restrict__ btot,
    int4* __restrict__ brec, int E, int NB){
  __shared__ int off_l[NBMAX];
  const int tid = threadIdx.x;
  for (int k = tid; k < NB; k += 256)
    off_l[k] = btot[k] + cntB[blockIdx.x*NBMAX + k];
  __syncthreads();
  const int4*   src4 = (const int4*)src;
  const int4*   dst4 = (const int4*)dst;
  const float4* w0p  = (const float4*)(ew);
  const float4* w1p  = (const float4*)(ew + (size_t)E);
  const float4* w2p  = (const float4*)(ew + 2*(size_t)E);
  const float4* w3p  = (const float4*)(ew + 3*(size_t)E);
  const int E4 = E >> 2;
  for (int g = blockIdx.x*256 + tid; g < E4; g += NBLK_E*256){
    int4 s4 = src4[g];
    int4 d4 = dst4[g];
    float4 w0 = w0p[g], w1 = w1p[g], w2 = w2p[g], w3 = w3p[g];
    p3_emit(s4.x, d4.x, w0.x, w1.x, w2.x, w3.x, off_l, brec);
    p3_emit(s4.y, d4.y, w0.y, w1.y, w2.y, w3.y, off_l, brec);
    p3_emit(s4.z, d4.z, w0.z, w1.z, w2.z, w3.z, off_l, brec);
    p3_emit(s4.w, d4.w, w0.w, w1.w, w2.w, w3.w, off_l, brec);
  }
  if (blockIdx.x == 0 && tid < (E & 3)){
    int e = (E & ~3) + tid;
    p3_emit(src[e], dst[e], ew[e], ew[(size_t)E + e],
            ew[2*(size_t)E + e], ew[3*(size_t)E + e], off_l, brec);
  }
}

__global__ __launch_bounds__(256) void p4_bsort_kernel(
    const int4* __restrict__ brec, const int* __restrict__ btot,
    int* __restrict__ csr_src, uint2* __restrict__ csr_w,
    int* __restrict__ rowptr, int E, int NB, int N){
  __shared__ int  h[128];
  __shared__ int  h2[128];
  __shared__ int  s[256];
  __shared__ int4 rec[CAP];
  const int k   = blockIdx.x;
  const int tid = threadIdx.x;
  const int beg = btot[k];
  const int end = (k + 1 < NB) ? btot[k + 1] : E;
  int count = end - beg;
  if (count > CAP) count = CAP;

  if (tid < 128) h[tid] = 0;
  __syncthreads();
  for (int t = tid; t < count; t += 256){
    int4 R = brec[beg + t];
    rec[t] = R;
    atomicAdd(&h[R.w & 127], 1);
  }
  __syncthreads();
  int v = (tid < 128) ? h[tid] : 0;
  s[tid] = v;
  __syncthreads();
  for (int off = 1; off < 256; off <<= 1){
    int x = (tid >= off) ? s[tid - off] : 0;
    __syncthreads();
    s[tid] += x;
    __syncthreads();
  }
  if (tid < 128){
    int excl = s[tid] - v;
    h2[tid] = excl;
    int idx = (k << 7) + tid;
    if (idx < N) rowptr[idx] = beg + excl;
  }
  if (k == 0 && tid == 128) rowptr[N] = E;
  __syncthreads();
  for (int t = tid; t < count; t += 256){
    int4 R = rec[t];
    int lp = atomicAdd(&h2[R.w & 127], 1);
    csr_src[beg + lp] = R.x;
    csr_w[beg + lp]   = make_uint2((unsigned)R.y, (unsigned)R.z);
  }
}

// ================= legacy CSR build (fallback, small ws) =================

__global__ void hist_kernel(const int* __restrict__ dst, int* __restrict__ cnt,
                            int* __restrict__ rank, int E){
  int e = blockIdx.x*blockDim.x + threadIdx.x;
  if (e < E) rank[e] = atomicAdd(&cnt[dst[e]], 1);
}

__global__ void scatter_kernel(const int* __restrict__ src, const int* __restrict__ dst,
                               const int* __restrict__ rank, const int* __restrict__ rowptr,
                               int2* __restrict__ csr_se, int E){
  int e = blockIdx.x*blockDim.x + threadIdx.x;
  if (e >= E) return;
  int pos = rowptr[dst[e]] + rank[e];
  csr_se[pos] = make_int2(src[e], e);
}

__global__ void build_kernel(const int2* __restrict__ csr_se, const float* __restrict__ ew,
                             int* __restrict__ csr_src, uint2* __restrict__ csr_w, int E){
  int p = blockIdx.x*blockDim.x + threadIdx.x;
  if (p >= E) return;
  int2 se = csr_se[p];
  csr_src[p] = se.x;
  size_t e = (size_t)se.y;
  unsigned a = f2b(ew[e])               | (f2b(ew[(size_t)E + e]) << 16);
  unsigned b = f2b(ew[2*(size_t)E + e]) | (f2b(ew[3*(size_t)E + e]) << 16);
  csr_w[p] = make_uint2(a, b);
}

__global__ void scan1_kernel(int* __restrict__ data, int* __restrict__ bsum, int total){
  __shared__ int s[256];
  int i = blockIdx.x*256 + threadIdx.x;
  int v = (i < total) ? data[i] : 0;
  s[threadIdx.x] = v;
  __syncthreads();
  for (int off=1; off<256; off<<=1){
    int t = (threadIdx.x >= (unsigned)off) ? s[threadIdx.x - off] : 0;
    __syncthreads();
    s[threadIdx.x] += t;
    __syncthreads();
  }
  if (i < total) data[i] = s[threadIdx.x] - v;
  if (threadIdx.x == 255) bsum[blockIdx.x] = s[255];
}

__global__ void scan2_kernel(int* __restrict__ bsum, int nb){
  __shared__ int s[1024];
  int t = threadIdx.x;
  int v = (t < nb) ? bsum[t] : 0;
  s[t] = v;
  __syncthreads();
  for (int off=1; off<1024; off<<=1){
    int x = (t >= off) ? s[t - off] : 0;
    __syncthreads();
    s[t] += x;
    __syncthreads();
  }
  if (t < nb) bsum[t] = s[t] - v;
}

__global__ void scan3_kernel(int* __restrict__ rowptr, const int* __restrict__ bsum, int total){
  int i = blockIdx.x*256 + threadIdx.x;
  if (i < total) rowptr[i] += bsum[blockIdx.x];
}

// ================= W prep (all 5 layers in one launch) =================

static __device__ __forceinline__ void wtprep_one(
    const float* W, unsigned short* wtp, int t, int DIN, int DOUT, int XPI, int K){
  int j = t / K, k = t % K;
  int r = k / XPI, i = k % XPI;
  float v = (j < DOUT && i < XPI && i < DIN) ? W[(r*DIN + i)*DOUT + j] : 0.f;
  wtp[t] = (unsigned short)f2b(v);
}

__global__ __launch_bounds__(256) void wtprep_all_kernel(
    const float* __restrict__ W1, const float* __restrict__ W2,
    const float* __restrict__ W3, const float* __restrict__ W4,
    const float* __restrict__ W5,
    unsigned short* __restrict__ wtp1, unsigned short* __restrict__ wtp2,
    unsigned short* __restrict__ wtp3, unsigned short* __restrict__ wtp4,
    unsigned short* __restrict__ wtp5){
  int t = blockIdx.x*256 + threadIdx.x;
  if (t < 8192){ wtprep_one(W1, wtp1, t, 64, 20, 64, 256); return; }
  t -= 8192;
  if (t < 2048){ wtprep_one(W2, wtp2, t, 20, 16, 32, 128); return; }
  t -= 2048;
  if (t < 1024){ wtprep_one(W3, wtp3, t, 16, 12, 16, 64); return; }
  t -= 1024;
  if (t < 1024){ wtprep_one(W4, wtp4, t, 12, 8, 16, 64); return; }
  t -= 1024;
  if (t < 1024){ wtprep_one(W5, wtp5, t, 8, 4, 16, 64); return; }
}

// ================= concat (fp32 inputs -> bf16 xcat) =================

__global__ __launch_bounds__(256) void concat_kernel(
    const float* __restrict__ oh, const float* __restrict__ f,
    unsigned short* __restrict__ xcat, int N){
  int i = blockIdx.x*256 + threadIdx.x;
  if (i >= N*64) return;
  int n = i >> 6, j = i & 63;
  float v = (j < 20) ? oh[n*20 + j] : f[n*44 + (j-20)];
  xcat[i] = (unsigned short)f2b(v);
}

// ================= layerA (L1): 4xES-unrolled gather -> z bf16 global =================

template<int XPI, int NPW>
__global__ __launch_bounds__(256) void layerA_kernel(
    const int* __restrict__ rowptr, const int* __restrict__ csr_src,
    const uint2* __restrict__ csr_w, const unsigned short* __restrict__ x,
    unsigned short* __restrict__ z, int N)
{
  constexpr int RL   = XPI/4;
  constexpr int ES   = 64/RL;
  constexpr int NPB  = 4*NPW;
  constexpr int K    = 4*XPI;
  constexpr unsigned ROWB = RL*8;

  const int tid  = threadIdx.x;
  const int wave = tid >> 6;
  const int lane = tid & 63;
  const int sub  = lane / RL;
  const int q4   = lane & (RL - 1);
  const unsigned qoff = (unsigned)q4*8;
  const unsigned char* xb = (const unsigned char*)x;

  #pragma unroll
  for (int t = 0; t < NPW; ++t){
    const int slot = wave*NPW + t;
    const int node = blockIdx.x*NPB + slot;
    if (node < N){
      const int beg = rowptr[node];
      const int end = rowptr[node+1];
      f32x2 AL0{0.f,0.f}, AL1{0.f,0.f}, AL2{0.f,0.f}, AL3{0.f,0.f};
      f32x2 AH0{0.f,0.f}, AH1{0.f,0.f}, AH2{0.f,0.f}, AH3{0.f,0.f};
      int k = beg;
      for (; k + 4*ES <= end; k += 4*ES){
        int kk0 = k + sub, kk1 = k + ES + sub, kk2 = k + 2*ES + sub, kk3 = k + 3*ES + sub;
        int s0 = csr_src[kk0], s1 = csr_src[kk1], s2 = csr_src[kk2], s3 = csr_src[kk3];
        uint2 wp0 = csr_w[kk0], wp1 = csr_w[kk1], wp2 = csr_w[kk2], wp3 = csr_w[kk3];
        uint2 u0 = *(const uint2*)(xb + ((unsigned)s0*ROWB + qoff));
        uint2 u1 = *(const uint2*)(xb + ((unsigned)s1*ROWB + qoff));
        uint2 u2 = *(const uint2*)(xb + ((unsigned)s2*ROWB + qoff));
        uint2 u3 = *(const uint2*)(xb + ((unsigned)s3*ROWB + qoff));
        acc_edge(u0, wp0, AL0, AH0, AL1, AH1, AL2, AH2, AL3, AH3);
        acc_edge(u1, wp1, AL0, AH0, AL1, AH1, AL2, AH2, AL3, AH3);
        acc_edge(u2, wp2, AL0, AH0, AL1, AH1, AL2, AH2, AL3, AH3);
        acc_edge(u3, wp3, AL0, AH0, AL1, AH1, AL2, AH2, AL3, AH3);
      }
      for (; k + 2*ES <= end; k += 2*ES){
        int kk0 = k + sub, kk1 = k + ES + sub;
        int s0 = csr_src[kk0], s1 = csr_src[kk1];
        uint2 wp0 = csr_w[kk0], wp1 = csr_w[kk1];
        uint2 u0 = *(const uint2*)(xb + ((unsigned)s0*ROWB + qoff));
        uint2 u1 = *(const uint2*)(xb + ((unsigned)s1*ROWB + qoff));
        acc_edge(u0, wp0, AL0, AH0, AL1, AH1, AL2, AH2, AL3, AH3);
        acc_edge(u1, wp1, AL0, AH0, AL1, AH1, AL2, AH2, AL3, AH3);
      }
      for (; k < end; k += ES){
        int kk = k + sub;
        int s = 0;
        uint2 wp = make_uint2(0u, 0u);
        if (kk < end){ s = csr_src[kk]; wp = csr_w[kk]; }
        uint2 u = *(const uint2*)(xb + ((unsigned)s*ROWB + qoff));
        acc_edge(u, wp, AL0, AH0, AL1, AH1, AL2, AH2, AL3, AH3);
      }
      wave_foldB<RL, 64>(AL0, AH0, AL1, AH1, AL2, AH2, AL3, AH3);
      if (sub == 0){
        uint2* zp = (uint2*)(z + (size_t)node*K);
        zp[0*RL + q4] = make_uint2(f2b(AL0.x) | (f2b(AL0.y)<<16), f2b(AH0.x) | (f2b(AH0.y)<<16));
        zp[1*RL + q4] = make_uint2(f2b(AL1.x) | (f2b(AL1.y)<<16), f2b(AH1.x) | (f2b(AH1.y)<<16));
        zp[2*RL + q4] = make_uint2(f2b(AL2.x) | (f2b(AL2.y)<<16), f2b(AH2.x) | (f2b(AH2.y)<<16));
        zp[3*RL + q4] = make_uint2(f2b(AL3.x) | (f2b(AL3.y)<<16), f2b(AH3.x) | (f2b(AH3.y)<<16));
      }
    }
  }
}

// ================= gemmB (L1 only): xout = ELU(z @ WtP + b) =================

template<int K, int NJT, int DOUT, int XPO>
__global__ __launch_bounds__(256) void gemmB_kernel(
    const unsigned short* __restrict__ zbuf, const unsigned short* __restrict__ wtp,
    const float* __restrict__ bias, unsigned short* __restrict__ xout, int N)
{
  constexpr int RS   = K*2;
  constexpr int C16  = RS/16;
  constexpr int WT16 = NJT*16*C16;
  constexpr int ZT16 = 16*C16;
  __shared__ __align__(16) unsigned char wt[NJT*16*RS];
  __shared__ __align__(16) unsigned char zt[4][16*RS];

  const int tid  = threadIdx.x;
  const int wave = tid >> 6;
  const int lane = tid & 63;

  const uint4* wsrc = (const uint4*)wtp;
  for (int u = tid; u < WT16; u += 256){
    int row = u / C16, c = u % C16;
    *(uint4*)(wt + ((row*RS + c*16) ^ ((row & 7) << 4))) = wsrc[u];
  }
  const int node_base = (blockIdx.x*4 + wave)*16;
  const uint4* zsrc = (const uint4*)(zbuf + (size_t)node_base*K);
  for (int u = lane; u < ZT16; u += 64){
    int row = u / C16, c = u % C16;
    *(uint4*)(zt[wave] + ((row*RS + c*16) ^ ((row & 7) << 4))) = zsrc[u];
  }
  __syncthreads();

  const int rA = lane & 15;
  const int g  = lane >> 4;
  f32x4 acc[NJT];
  #pragma unroll
  for (int jt = 0; jt < NJT; ++jt) acc[jt] = f32x4{0.f, 0.f, 0.f, 0.f};

  #pragma unroll
  for (int ks = 0; ks < K/32; ++ks){
    short8v a = *(const short8v*)(zt[wave] + ((rA*RS + ks*64 + g*16) ^ ((rA & 7) << 4)));
    #pragma unroll
    for (int jt = 0; jt < NJT; ++jt){
      int rB = rA + jt*16;
      short8v bf = *(const short8v*)(wt + ((rB*RS + ks*64 + g*16) ^ ((rB & 7) << 4)));
      acc[jt] = __builtin_amdgcn_mfma_f32_16x16x32_bf16(a, bf, acc[jt], 0, 0, 0);
    }
  }

  #pragma unroll
  for (int jt = 0; jt < NJT; ++jt){
    int j = rA + jt*16;
    float bj = (j < DOUT) ? bias[j] : 0.f;
    #pragma unroll
    for (int r = 0; r < 4; ++r){
      int node = node_base + g*4 + r;
      if (node < N && j < XPO){
        float v = elu_f(acc[jt][r] + bj);
        xout[(size_t)node*XPO + j] = (unsigned short)f2b(v);
      }
    }
  }
}

// ================= fused layer (L2-L5): partial fold + extended-K MFMA =================

template<int XPI, int NPW, int NJT, int DOUT, int XPO, int CLUST, bool FUSE_MLP>
__global__ __launch_bounds__(256) void fusedB_kernel(
    const int* __restrict__ rowptr, const int* __restrict__ csr_src,
    const uint2* __restrict__ csr_w, const unsigned short* __restrict__ x,
    const unsigned short* __restrict__ wtp, const float* __restrict__ bias,
    unsigned short* __restrict__ xout,
    const float* __restrict__ lw1, const float* __restrict__ lb1,
    const float* __restrict__ lw2, const float* __restrict__ lb2,
    const float* __restrict__ lw3, const float* __restrict__ lb3,
    float* __restrict__ mlp_out, int N)
{
  constexpr int RL   = XPI/4;
  constexpr int ES   = 64/RL;
  constexpr int NPB  = 4*NPW;
  constexpr int K    = 4*XPI;
  constexpr int KE   = K*CLUST;
  constexpr int RS   = KE*2;
  constexpr int C16  = RS/16;
  constexpr int C16B = (K*2)/16;
  constexpr int WT16 = NJT*16*C16;
  constexpr int SUBC = ES/CLUST;
  constexpr int BND  = RL*SUBC;
  constexpr unsigned ROWB = RL*8;
  __shared__ __align__(16) unsigned char wt[NJT*16*RS];
  __shared__ __align__(16) unsigned char zt[16*RS];

  const int tid  = threadIdx.x;
  const int wave = tid >> 6;
  const int lane = tid & 63;

  const uint4* wsrc = (const uint4*)wtp;
  for (int u = tid; u < WT16; u += 256){
    int row = u / C16, c = u % C16;
    *(uint4*)(wt + ((row*RS + c*16) ^ ((row & 7) << 4))) = wsrc[row*C16B + (c & (C16B - 1))];
  }

  const int sub = lane / RL;
  const int q4  = lane & (RL - 1);
  const unsigned qoff = (unsigned)q4*8;
  const unsigned char* xb = (const unsigned char*)x;
  const int node0 = blockIdx.x*NPB;

  int rp[NPW + 1];
  #pragma unroll
  for (int i = 0; i <= NPW; ++i){
    int idx = node0 + wave*NPW + i;
    rp[i] = rowptr[idx > N ? N : idx];
  }

  #pragma unroll
  for (int t = 0; t < NPW; ++t){
    const int slot = wave*NPW + t;
    const int node = node0 + slot;
    if (node < N){
      const int beg = rp[t];
      const int end = rp[t+1];
      f32x2 AL0{0.f,0.f}, AL1{0.f,0.f}, AL2{0.f,0.f}, AL3{0.f,0.f};
      f32x2 AH0{0.f,0.f}, AH1{0.f,0.f}, AH2{0.f,0.f}, AH3{0.f,0.f};
      int k = beg;
      for (; k + 2*ES <= end; k += 2*ES){
        int kk0 = k + sub, kk1 = k + ES + sub;
        int s0 = csr_src[kk0], s1 = csr_src[kk1];
        uint2 wp0 = csr_w[kk0], wp1 = csr_w[kk1];
        uint2 u0 = *(const uint2*)(xb + ((unsigned)s0*ROWB + qoff));
        uint2 u1 = *(const uint2*)(xb + ((unsigned)s1*ROWB + qoff));
        acc_edge(u0, wp0, AL0, AH0, AL1, AH1, AL2, AH2, AL3, AH3);
        acc_edge(u1, wp1, AL0, AH0, AL1, AH1, AL2, AH2, AL3, AH3);
      }
      for (; k < end; k += ES){
        int kk = k + sub;
        int s = 0;
        uint2 wp = make_uint2(0u, 0u);
        if (kk < end){ s = csr_src[kk]; wp = csr_w[kk]; }
        uint2 u = *(const uint2*)(xb + ((unsigned)s*ROWB + qoff));
        acc_edge(u, wp, AL0, AH0, AL1, AH1, AL2, AH2, AL3, AH3);
      }
      wave_foldB<RL, BND>(AL0, AH0, AL1, AH1, AL2, AH2, AL3, AH3);
      if ((sub & (SUBC - 1)) == 0){
        const int cid = sub / SUBC;
        uint2 c0 = make_uint2(f2b(AL0.x) | (f2b(AL0.y)<<16), f2b(AH0.x) | (f2b(AH0.y)<<16));
        uint2 c1 = make_uint2(f2b(AL1.x) | (f2b(AL1.y)<<16), f2b(AH1.x) | (f2b(AH1.y)<<16));
        uint2 c2 = make_uint2(f2b(AL2.x) | (f2b(AL2.y)<<16), f2b(AH2.x) | (f2b(AH2.y)<<16));
        uint2 c3 = make_uint2(f2b(AL3.x) | (f2b(AL3.y)<<16), f2b(AH3.x) | (f2b(AH3.y)<<16));
        const int sw = (slot & 7) << 4;
        const int kb = cid*K*2;
        int bc0 = kb + (0*XPI + q4*4)*2;
        int bc1 = kb + (1*XPI + q4*4)*2;
        int bc2 = kb + (2*XPI + q4*4)*2;
        int bc3 = kb + (3*XPI + q4*4)*2;
        *(uint2*)(zt + (((slot*RS + (bc0 & ~15)) ^ sw) + (bc0 & 15))) = c0;
        *(uint2*)(zt + (((slot*RS + (bc1 & ~15)) ^ sw) + (bc1 & 15))) = c1;
        *(uint2*)(zt + (((slot*RS + (bc2 & ~15)) ^ sw) + (bc2 & 15))) = c2;
        *(uint2*)(zt + (((slot*RS + (bc3 & ~15)) ^ sw) + (bc3 & 15))) = c3;
      }
    }
  }
  __syncthreads();

  if (wave == 0){
    const int rA = lane & 15;
    const int g  = lane >> 4;
    f32x4 acc[NJT];
    #pragma unroll
    for (int jt = 0; jt < NJT; ++jt) acc[jt] = f32x4{0.f, 0.f, 0.f, 0.f};

    #pragma unroll
    for (int ks = 0; ks < KE/32; ++ks){
      short8v a = *(const short8v*)(zt + ((rA*RS + ks*64 + g*16) ^ ((rA & 7) << 4)));
      #pragma unroll
      for (int jt = 0; jt < NJT; ++jt){
        int rB = rA + jt*16;
        short8v bf = *(const short8v*)(wt + ((rB*RS + ks*64 + g*16) ^ ((rB & 7) << 4)));
        acc[jt] = __builtin_amdgcn_mfma_f32_16x16x32_bf16(a, bf, acc[jt], 0, 0, 0);
      }
    }

    if (!FUSE_MLP){
      #pragma unroll
      for (int jt = 0; jt < NJT; ++jt){
        int j = rA + jt*16;
        float bj = (j < DOUT) ? bias[j] : 0.f;
        #pragma unroll
        for (int r = 0; r < 4; ++r){
          int row = g*4 + r;
          int node = node0 + row;
          if (row < NPB && node < N && j < XPO){
            float v = elu_f(acc[jt][r] + bj);
            xout[(size_t)node*XPO + j] = (unsigned short)f2b(v);
          }
        }
      }
    } else {
      float bj = (rA < DOUT) ? bias[rA] : 0.f;
      float val[4];
      #pragma unroll
      for (int r = 0; r < 4; ++r) val[r] = elu_f(acc[0][r] + bj);
      const int base = lane & 48;
      float x0 = 0.f, x1 = 0.f, x2 = 0.f, x3 = 0.f;
      #pragma unroll
      for (int q = 0; q < 4; ++q){
        float t0 = __shfl(val[q], base + 0, 64);
        float t1 = __shfl(val[q], base + 1, 64);
        float t2 = __shfl(val[q], base + 2, 64);
        float t3 = __shfl(val[q], base + 3, 64);
        if (rA == q){ x0 = t0; x1 = t1; x2 = t2; x3 = t3; }
      }
      if (rA < 4){
        int node = node0 + g*4 + rA;
        if (node < N){
          float xin[4] = {x0, x1, x2, x3};
          float h1[8];
          #pragma unroll
          for (int j = 0; j < 8; ++j){
            float a = lb1[j];
            #pragma unroll
            for (int i = 0; i < 4; ++i) a += xin[i]*lw1[i*8 + j];
            h1[j] = elu_f(a);
          }
          float h2[4];
          #pragma unroll
          for (int j = 0; j < 4; ++j){
            float a = lb2[j];
            #pragma unroll
            for (int i = 0; i < 8; ++i) a += h1[i]*lw2[i*4 + j];
            h2[j] = elu_f(a);
          }
          float a = lb3[0];
          #pragma unroll
          for (int i = 0; i < 4; ++i) a += h2[i]*lw3[i];
          mlp_out[node] = 1.0f / (1.0f + expf(-a));
        }
      }
    }
  }
}

// ================= standalone MLP (legacy fallback path only) =================

__global__ __launch_bounds__(256) void mlp_kernel(
    const unsigned short* __restrict__ x,
    const float* __restrict__ lw1, const float* __restrict__ lb1,
    const float* __restrict__ lw2, const float* __restrict__ lb2,
    const float* __restrict__ lw3, const float* __restrict__ lb3,
    float* __restrict__ out, int N){
  int n = blockIdx.x*blockDim.x + threadIdx.x;
  if (n >= N) return;
  uint2 u = ((const uint2*)x)[n];
  float x0[4] = {bf_lo(u.x), bf_hi(u.x), bf_lo(u.y), bf_hi(u.y)};
  float h1[8];
  #pragma unroll
  for (int j=0;j<8;j++){
    float a = lb1[j];
    #pragma unroll
    for (int i=0;i<4;i++) a += x0[i]*lw1[i*8+j];
    h1[j] = elu_f(a);
  }
  float h2[4];
  #pragma unroll
  for (int j=0;j<4;j++){
    float a = lb2[j];
    #pragma unroll
    for (int i=0;i<8;i++) a += h1[i]*lw2[i*4+j];
    h2[j] = elu_f(a);
  }
  float a = lb3[0];
  #pragma unroll
  for (int i=0;i<4;i++) a += h2[i]*lw3[i];
  out[n] = 1.0f / (1.0f + expf(-a));
}

// ================= launch =================

extern "C" void kernel_launch(void* const* d_in, const int* in_sizes, int n_in,
                              void* d_out, int out_size, void* d_ws, size_t ws_size,
                              hipStream_t stream){
  const float* one_hot  = DF(d_in[0]);
  const float* features = DF(d_in[1]);
  const int*   src      = DI(d_in[3]);
  const int*   dst      = DI(d_in[4]);
  const float* ew       = DF(d_in[5]);
  const float* W1 = DF(d_in[6]);  const float* b1 = DF(d_in[7]);
  const float* W2 = DF(d_in[8]);  const float* b2 = DF(d_in[9]);
  const float* W3 = DF(d_in[10]); const float* b3 = DF(d_in[11]);
  const float* W4 = DF(d_in[12]); const float* b4 = DF(d_in[13]);
  const float* W5 = DF(d_in[14]); const float* b5 = DF(d_in[15]);
  const float* lw1 = DF(d_in[16]); const float* lb1 = DF(d_in[17]);
  const float* lw2 = DF(d_in[18]); const float* lb2 = DF(d_in[19]);
  const float* lw3 = DF(d_in[20]); const float* lb3 = DF(d_in[21]);
  float* out = (float*)d_out;

  const int N = in_sizes[0] / 20;   // 100000
  const int E = in_sizes[3];        // 3200000
  const int NB = (N + 127) >> 7;
  const int zN = ((N + 63)/64)*64;

  auto align = [](size_t x){ return (x + 255) & ~((size_t)255); };
  char* ws = (char*)d_ws;
  size_t off = 0;
  int*    rowptr  = (int*)(ws + off);    off = align(off + (size_t)(N+1)*4);
  int*    bsum    = (int*)(ws + off);    off = align(off + 4096);
  int*    csr_src = (int*)(ws + off);    off = align(off + (size_t)E*4);
  uint2*  csr_w   = (uint2*)(ws + off);  off = align(off + (size_t)E*8);
  unsigned short* wtp1 = (unsigned short*)(ws + off); off = align(off + 32*256*2);
  unsigned short* wtp2 = (unsigned short*)(ws + off); off = align(off + 16*128*2);
  unsigned short* wtp3 = (unsigned short*)(ws + off); off = align(off + 16*64*2);
  unsigned short* wtp4 = (unsigned short*)(ws + off); off = align(off + 16*64*2);
  unsigned short* wtp5 = (unsigned short*)(ws + off); off = align(off + 16*64*2);
  char*   regD    = ws + off;            off = align(off + (size_t)E*8);
  int2*   csr_se  = (int2*)regD;
  unsigned short* xcat = (unsigned short*)regD;
  char*   regE    = ws + off;            off = align(off + (size_t)E*4);
  int*    rank    = (int*)regE;
  unsigned short* xA = (unsigned short*)regE;
  unsigned short* xB = (unsigned short*)(ws + off); off = align(off + (size_t)N*16*2);
  unsigned short* xC = (unsigned short*)(ws + off); off = align(off + (size_t)N*16*2);
  char*   regF    = ws + off;            // legacy zbuf region
  size_t  off1 = align(off + (size_t)E*8);
  int*    cntB    = (int*)(ws + off1);   off1 = align(off1 + (size_t)NBLK_E*NBMAX*4);
  int*    btot    = (int*)(ws + off1);   off1 = align(off1 + (size_t)NBMAX*4);
  char*   regG    = ws + off1;
  int4*   brec    = (int4*)regG;
  size_t gsz = (size_t)E*16; if ((size_t)zN*512 > gsz) gsz = (size_t)zN*512;
  off1 = align(off1 + gsz);
  size_t  need_bucket = off1;

  const int TB = 256;
  const int nbE = (E + TB - 1) / TB;
  const int nbN = (N + TB - 1) / TB;
  const int total = N + 1;
  const int nb1 = (total + 255) / 256;
  const bool bucket_path = (ws_size >= need_bucket) && (NB <= NBMAX);
  unsigned short* zbuf = bucket_path ? (unsigned short*)regG : (unsigned short*)regF;

  wtprep_all_kernel<<<(13312 + 255)/256, TB, 0, stream>>>(
      W1, W2, W3, W4, W5, wtp1, wtp2, wtp3, wtp4, wtp5);

  if (bucket_path){
    p1_bhist4_kernel<<<NBLK_E, TB, 0, stream>>>(dst, cntB, E, NB);
    p2_bscan_kernel<<<NB, TB, 0, stream>>>(cntB, btot, NB);
    scan2_kernel<<<1, 1024, 0, stream>>>(btot, NB);
    p3_bscatter4_kernel<<<NBLK_E, TB, 0, stream>>>(src, dst, ew, cntB, btot, brec, E, NB);
    p4_bsort_kernel<<<NB, TB, 0, stream>>>(brec, btot, csr_src, csr_w, rowptr, E, NB, N);
  } else {
    hipMemsetAsync(rowptr, 0, (size_t)(N+1)*4, stream);
    hist_kernel<<<nbE, TB, 0, stream>>>(dst, rowptr, rank, E);
    scan1_kernel<<<nb1, 256, 0, stream>>>(rowptr, bsum, total);
    scan2_kernel<<<1, 1024, 0, stream>>>(bsum, nb1);
    scan3_kernel<<<nb1, 256, 0, stream>>>(rowptr, bsum, total);
    scatter_kernel<<<nbE, TB, 0, stream>>>(src, dst, rank, rowptr, csr_se, E);
    build_kernel<<<nbE, TB, 0, stream>>>(csr_se, ew, csr_src, csr_w, E);
  }

  concat_kernel<<<(N*64 + TB - 1)/TB, TB, 0, stream>>>(one_hot, features, xcat, N);

  const int NBB = (N + 63)/64;
  // L1: 64 -> 20 (split: layerA -> global z -> gemmB)
  layerA_kernel<64,1><<<(N+3)/4, TB, 0, stream>>>(rowptr, csr_src, csr_w, xcat, zbuf, N);
  gemmB_kernel<256,2,20,32><<<NBB, TB, 0, stream>>>(zbuf, wtp1, b1, xA, N);
  // L2-L4: fused, partial fold (CLUST clusters) + extended-K MFMA
  fusedB_kernel<32,2,1,16,16,2,false><<<(N+7)/8,   TB, 0, stream>>>(
      rowptr, csr_src, csr_w, xA, wtp2, b2, xB,
      nullptr, nullptr, nullptr, nullptr, nullptr, nullptr, nullptr, N);
  fusedB_kernel<16,4,1,12,16,4,false><<<(N+15)/16, TB, 0, stream>>>(
      rowptr, csr_src, csr_w, xB, wtp3, b3, xC,
      nullptr, nullptr, nullptr, nullptr, nullptr, nullptr, nullptr, N);
  fusedB_kernel<16,4,1, 8,16,4,false><<<(N+15)/16, TB, 0, stream>>>(
      rowptr, csr_src, csr_w, xC, wtp4, b4, xA,
      nullptr, nullptr, nullptr, nullptr, nullptr, nullptr, nullptr, N);
  // L5 + MLP fused: writes sigmoid output directly
  fusedB_kernel<16,4,1, 4, 4,4,true><<<(N+15)/16, TB, 0, stream>>>(
      rowptr, csr_src, csr_w, xA, wtp5, b5, nullptr,
      lw1, lb1, lw2, lb2, lw3, lb3, out, N);
}